// Round 5
// baseline (220.511 us; speedup 1.0000x reference)
//
#include <hip/hip_runtime.h>

// Problem constants (fixed by setup_inputs): B=32, C=256, H=W=64
#define BATCH 32
#define CHAN  256
#define HGT   64
#define WID   64
#define HW    4096   // HGT*WID
#define CPB   16     // channels per block == waves per block

// Fully fused, one-wave-per-channel:
//   grid = 32 batches x 16 block-groups = 512 blocks, 1024 threads (16 waves).
//   Phase A: all 1024 threads scatter the batch's bilinear weight map into
//            16 KiB LDS (4 points/thread, LDS float atomics).  One barrier.
//   Phase B: wave w streams channel c0+w's full 16 KiB plane with float4
//            loads and dots it against the LDS map (ds_read_b128) --
//            NO further barriers, register-only shuffle reduce, direct store.
//   A never goes to global memory; weight kernel + dependency stall removed.
//   512 blocks x 2 per CU = exactly resident; VGPR<=64 -> 32 waves/CU.
__global__ __launch_bounds__(1024, 8) void fused_bilinear_pool(
        const float* __restrict__ data,     // [B, C, H, W] fp32
        const float* __restrict__ offset,   // [B, 2, H, W] fp32
        const float* __restrict__ ts_ptr,   // scalar fp32
        float* __restrict__ out)            // [B, C] fp32
{
    const int blk = blockIdx.x;             // 0..511
    const int b   = blk >> 4;
    const int g   = blk & 15;               // block-group within batch
    const int tid = threadIdx.x;

    __shared__ float acc[HW];               // 16 KiB weight map (raw weights)

    acc[tid]        = 0.0f;
    acc[tid + 1024] = 0.0f;
    acc[tid + 2048] = 0.0f;
    acc[tid + 3072] = 0.0f;
    __syncthreads();

    float ts = ts_ptr[0];
    ts = fminf(fmaxf(ts, 0.001f), 0.01f);

    const float* off_y = offset + (size_t)b * 2 * HW;   // offset[b,0]
    const float* off_x = off_y + HW;                    // offset[b,1]

    // ---- Phase A: scatter (4 points per thread) ----
    #pragma unroll
    for (int it = 0; it < 4; ++it) {
        const int p = tid + it * 1024;
        const int i = p >> 6;
        const int j = p & 63;
        const float dy = off_y[p];
        const float dx = off_x[p];
        // reference eval order: clip(i + (ts*offset)*H, 0, H-1)
        float y = fminf(fmaxf((float)i + ts * dy * 64.0f, 0.0f), 63.0f);
        float x = fminf(fmaxf((float)j + ts * dx * 64.0f, 0.0f), 63.0f);
        int y0 = (int)floorf(y); y0 = min(max(y0, 0), HGT - 2);
        int x0 = (int)floorf(x); x0 = min(max(x0, 0), WID - 2);
        const float wy = y - (float)y0;
        const float wx = x - (float)x0;
        const int base = (y0 << 6) + x0;
        atomicAdd(&acc[base],           (1.0f - wy) * (1.0f - wx));
        atomicAdd(&acc[base + 1],       (1.0f - wy) * wx);
        atomicAdd(&acc[base + WID],     wy * (1.0f - wx));
        atomicAdd(&acc[base + WID + 1], wy * wx);
    }
    __syncthreads();   // the ONLY barrier before independent per-wave streams

    // ---- Phase B: one wave per channel ----
    const int w    = tid >> 6;      // wave id = channel within group
    const int lane = tid & 63;

    const float* plane = data + ((size_t)(b * CHAN + g * CPB + w)) * HW;

    float sum = 0.0f;
    #pragma unroll
    for (int k = 0; k < 4; ++k) {
        // 4 segments of 256 elems per chunk: 4 global float4 + 4 LDS float4
        const int i0 = k * 1024 + 0   + lane * 4;
        const int i1 = k * 1024 + 256 + lane * 4;
        const int i2 = k * 1024 + 512 + lane * 4;
        const int i3 = k * 1024 + 768 + lane * 4;

        const float4 d0 = *reinterpret_cast<const float4*>(plane + i0);
        const float4 d1 = *reinterpret_cast<const float4*>(plane + i1);
        const float4 d2 = *reinterpret_cast<const float4*>(plane + i2);
        const float4 d3 = *reinterpret_cast<const float4*>(plane + i3);
        const float4 a0 = *reinterpret_cast<const float4*>(acc + i0);
        const float4 a1 = *reinterpret_cast<const float4*>(acc + i1);
        const float4 a2 = *reinterpret_cast<const float4*>(acc + i2);
        const float4 a3 = *reinterpret_cast<const float4*>(acc + i3);

        sum = fmaf(a0.x, d0.x, sum); sum = fmaf(a0.y, d0.y, sum);
        sum = fmaf(a0.z, d0.z, sum); sum = fmaf(a0.w, d0.w, sum);
        sum = fmaf(a1.x, d1.x, sum); sum = fmaf(a1.y, d1.y, sum);
        sum = fmaf(a1.z, d1.z, sum); sum = fmaf(a1.w, d1.w, sum);
        sum = fmaf(a2.x, d2.x, sum); sum = fmaf(a2.y, d2.y, sum);
        sum = fmaf(a2.z, d2.z, sum); sum = fmaf(a2.w, d2.w, sum);
        sum = fmaf(a3.x, d3.x, sum); sum = fmaf(a3.y, d3.y, sum);
        sum = fmaf(a3.z, d3.z, sum); sum = fmaf(a3.w, d3.w, sum);
    }

    // wave-64 register-only shuffle reduce
    #pragma unroll
    for (int off = 32; off > 0; off >>= 1)
        sum += __shfl_down(sum, off, 64);

    if (lane == 0)
        out[(b << 8) + g * CPB + w] = sum * (1.0f / (float)HW);  // fold mean
}

extern "C" void kernel_launch(void* const* d_in, const int* in_sizes, int n_in,
                              void* d_out, int out_size, void* d_ws, size_t ws_size,
                              hipStream_t stream) {
    const float* data   = (const float*)d_in[0];  // fp32 [32,256,64,64]
    const float* offset = (const float*)d_in[1];  // fp32 [32,2,64,64]
    const float* ts     = (const float*)d_in[2];  // fp32 scalar

    float* out = (float*)d_out;                   // [32, 256] fp32
    (void)d_ws; (void)ws_size;                    // workspace intentionally unused

    fused_bilinear_pool<<<BATCH * CPB, 1024, 0, stream>>>(data, offset, ts, out);
}

// Round 6
// 212.543 us; speedup vs baseline: 1.0375x; 1.0375x over previous
//
#include <hip/hip_runtime.h>

// Problem constants (fixed by setup_inputs): B=32, C=256, H=W=64
#define BATCH 32
#define CHAN  256
#define HGT   64
#define WID   64
#define HW    4096   // HGT*WID

// Kernel 1: build per-batch scatter-accumulated bilinear weight map A[b, 0:4096].
// One block per batch, 1024 threads. Stride-1024 p-loop keeps col == lane ->
// cheap LDS bank aliasing. Mean (1/4096) is folded into the map.
__global__ __launch_bounds__(1024) void weight_map_kernel(
        const float* __restrict__ offset,   // [B, 2, H, W] fp32
        const float* __restrict__ ts_ptr,   // scalar fp32
        float* __restrict__ A)              // [B, 4096] fp32 (d_ws)
{
    const int b   = blockIdx.x;
    const int tid = threadIdx.x;

    __shared__ float acc[HW];   // 16 KiB
    acc[tid]        = 0.0f;
    acc[tid + 1024] = 0.0f;
    acc[tid + 2048] = 0.0f;
    acc[tid + 3072] = 0.0f;
    __syncthreads();

    float ts = ts_ptr[0];
    ts = fminf(fmaxf(ts, 0.001f), 0.01f);

    const float* off_y = offset + (size_t)b * 2 * HW;   // offset[b,0]
    const float* off_x = off_y + HW;                    // offset[b,1]

    #pragma unroll
    for (int it = 0; it < 4; ++it) {
        const int p = tid + it * 1024;
        const int i = p >> 6;
        const int j = p & 63;
        const float dy = off_y[p];
        const float dx = off_x[p];
        // reference eval order: clip(i + (ts*offset)*H, 0, H-1)
        float y = fminf(fmaxf((float)i + ts * dy * 64.0f, 0.0f), 63.0f);
        float x = fminf(fmaxf((float)j + ts * dx * 64.0f, 0.0f), 63.0f);
        int y0 = (int)floorf(y); y0 = min(max(y0, 0), HGT - 2);
        int x0 = (int)floorf(x); x0 = min(max(x0, 0), WID - 2);
        const float wy = y - (float)y0;
        const float wx = x - (float)x0;
        const int base = (y0 << 6) + x0;
        atomicAdd(&acc[base],           (1.0f - wy) * (1.0f - wx));
        atomicAdd(&acc[base + 1],       (1.0f - wy) * wx);
        atomicAdd(&acc[base + WID],     wy * (1.0f - wx));
        atomicAdd(&acc[base + WID + 1], wy * wx);
    }
    __syncthreads();

    float* Ab = A + (size_t)b * HW;
    const float s = 1.0f / (float)HW;   // fold the mean into the weight map
    Ab[tid]        = acc[tid]        * s;
    Ab[tid + 1024] = acc[tid + 1024] * s;
    Ab[tid + 2048] = acc[tid + 2048] * s;
    Ab[tid + 3072] = acc[tid + 3072] * s;
}

// Kernel 2: O[b,c] = dot(A[b,:], data[b,c,:]).
// DEEP-MLP version. Block = 256 threads = 4 waves, 4 consecutive planes of
// one batch. Prologue: copy A[b] (L2-hot) into LDS once per block -> A reads
// ride lgkmcnt, fully decoupled from the data stream's vmcnt. Main: each
// wave issues ALL 16 data float4 loads into registers (statically indexed,
// 64 VGPR in flight) BEFORE consuming, then drains against LDS with 4
// rotating accumulators. launch_bounds(256,4) -> <=128 VGPR, 16 waves/CU,
// 256 KB of reads outstanding per CU.
__global__ __launch_bounds__(256, 4) void dot_kernel(
        const float* __restrict__ data,   // [B, C, H, W] fp32
        const float* __restrict__ A,      // [B, 4096] fp32
        float* __restrict__ out)          // [B, C] fp32
{
    const int blk = blockIdx.x;           // 0..2047 ; planes blk*4 .. blk*4+3
    const int b   = blk >> 6;             // 64 blocks per batch
    const int tid = threadIdx.x;
    const int w   = tid >> 6;             // wave id 0..3
    const int lane = tid & 63;

    __shared__ __align__(16) float As[HW];   // 16 KiB: A[b] staged in LDS

    // ---- stage A[b] into LDS (16 hot float4 loads per thread-group) ----
    {
        const float* Ab = A + (size_t)b * HW;
        #pragma unroll
        for (int s = 0; s < 4; ++s) {
            const int idx = (s * 256 + tid) * 4;
            *reinterpret_cast<float4*>(As + idx) =
                *reinterpret_cast<const float4*>(Ab + idx);
        }
    }
    __syncthreads();

    // ---- stream one plane per wave, 16 loads fully in flight ----
    const float* plane = data + (size_t)(blk * 4 + w) * HW;

    float4 d[16];
    #pragma unroll
    for (int s = 0; s < 16; ++s)
        d[s] = *reinterpret_cast<const float4*>(plane + s * 256 + lane * 4);

    float a0 = 0.0f, a1 = 0.0f, a2 = 0.0f, a3 = 0.0f;
    #pragma unroll
    for (int s = 0; s < 16; ++s) {
        const float4 av = *reinterpret_cast<const float4*>(As + s * 256 + lane * 4);
        // rotate accumulators to break the serial FMA dependence chain
        if ((s & 3) == 0) {
            a0 = fmaf(av.x, d[s].x, a0); a0 = fmaf(av.y, d[s].y, a0);
            a0 = fmaf(av.z, d[s].z, a0); a0 = fmaf(av.w, d[s].w, a0);
        } else if ((s & 3) == 1) {
            a1 = fmaf(av.x, d[s].x, a1); a1 = fmaf(av.y, d[s].y, a1);
            a1 = fmaf(av.z, d[s].z, a1); a1 = fmaf(av.w, d[s].w, a1);
        } else if ((s & 3) == 2) {
            a2 = fmaf(av.x, d[s].x, a2); a2 = fmaf(av.y, d[s].y, a2);
            a2 = fmaf(av.z, d[s].z, a2); a2 = fmaf(av.w, d[s].w, a2);
        } else {
            a3 = fmaf(av.x, d[s].x, a3); a3 = fmaf(av.y, d[s].y, a3);
            a3 = fmaf(av.z, d[s].z, a3); a3 = fmaf(av.w, d[s].w, a3);
        }
    }
    float sum = (a0 + a1) + (a2 + a3);

    // wave-64 register-only shuffle reduce; no barrier after staging
    #pragma unroll
    for (int off = 32; off > 0; off >>= 1)
        sum += __shfl_down(sum, off, 64);

    if (lane == 0) out[blk * 4 + w] = sum;
}

extern "C" void kernel_launch(void* const* d_in, const int* in_sizes, int n_in,
                              void* d_out, int out_size, void* d_ws, size_t ws_size,
                              hipStream_t stream) {
    const float* data   = (const float*)d_in[0];  // fp32 [32,256,64,64]
    const float* offset = (const float*)d_in[1];  // fp32 [32,2,64,64]
    const float* ts     = (const float*)d_in[2];  // fp32 scalar

    float* A   = (float*)d_ws;   // [32, 4096] fp32 = 512 KiB scratch
    float* out = (float*)d_out;  // [32, 256] fp32

    weight_map_kernel<<<BATCH, 1024, 0, stream>>>(offset, ts, A);
    // 4 planes per block -> 2048 blocks
    dot_kernel<<<(BATCH * CHAN) / 4, 256, 0, stream>>>(data, A, out);
}

// Round 7
// 204.123 us; speedup vs baseline: 1.0803x; 1.0413x over previous
//
#include <hip/hip_runtime.h>

// Problem constants (fixed by setup_inputs): B=32, C=256, H=W=64
#define BATCH 32
#define CHAN  256
#define HGT   64
#define WID   64
#define HW    4096   // HGT*WID
#define CPB   16     // channels per block == waves per block

// Fused v3: one 1024-thread block per (batch, 16-channel group); 512 blocks.
//   1) zero LDS map, barrier (nothing in flight -> no vmcnt drain)
//   2) issue offset float4 loads FIRST, then ALL 16 data float4 loads
//      (16 KB in flight per wave, ~256 KB per CU)
//   3) scatter phase consumes offsets via vmcnt(16) -- it runs UNDER the
//      data loads' flight time (software pipelining across the barrier)
//   4) barrier, then drain: 16 x (ds_read_b128 + 16 FMA, rotating accs),
//      wave-64 shuffle reduce, direct store.  No workspace, single dispatch.
__global__ __launch_bounds__(1024, 4) void fused_bilinear_pool(
        const float* __restrict__ data,     // [B, C, H, W] fp32
        const float* __restrict__ offset,   // [B, 2, H, W] fp32
        const float* __restrict__ ts_ptr,   // scalar fp32
        float* __restrict__ out)            // [B, C] fp32
{
    const int blk  = blockIdx.x;            // 0..511
    const int b    = blk >> 4;
    const int g    = blk & 15;              // channel group within batch
    const int tid  = threadIdx.x;
    const int w    = tid >> 6;              // wave id = channel within group
    const int lane = tid & 63;

    __shared__ float acc[HW];               // 16 KiB weight map

    // ---- zero the map; barrier with no vmem outstanding ----
    acc[tid]        = 0.0f;
    acc[tid + 1024] = 0.0f;
    acc[tid + 2048] = 0.0f;
    acc[tid + 3072] = 0.0f;
    __syncthreads();

    // ---- issue offset loads FIRST (they are the oldest vmem ops) ----
    const float* off_y = offset + (size_t)b * 2 * HW;   // offset[b,0]
    const float* off_x = off_y + HW;                    // offset[b,1]
    const float4 dy4 = *reinterpret_cast<const float4*>(off_y + tid * 4);
    const float4 dx4 = *reinterpret_cast<const float4*>(off_x + tid * 4);

    // ---- issue ALL 16 data loads (stay in flight through the scatter) ----
    const float* plane = data + ((size_t)(b * CHAN + g * CPB + w)) * HW;
    float4 d[16];
    #pragma unroll
    for (int s = 0; s < 16; ++s)
        d[s] = *reinterpret_cast<const float4*>(plane + s * 256 + lane * 4);

    float ts = ts_ptr[0];
    ts = fminf(fmaxf(ts, 0.001f), 0.01f);

    // ---- Phase A: scatter 4 contiguous points per thread ----
    // points p = 4*tid + e (e=0..3) share row i; waits only on dy4/dx4.
    {
        const int i  = tid >> 4;            // (4*tid) >> 6
        const int j0 = (tid << 2) & 63;
        const float dys[4] = {dy4.x, dy4.y, dy4.z, dy4.w};
        const float dxs[4] = {dx4.x, dx4.y, dx4.z, dx4.w};
        #pragma unroll
        for (int e = 0; e < 4; ++e) {
            // reference eval order: clip(i + (ts*offset)*H, 0, H-1)
            float y = fminf(fmaxf((float)i        + ts * dys[e] * 64.0f, 0.0f), 63.0f);
            float x = fminf(fmaxf((float)(j0 + e) + ts * dxs[e] * 64.0f, 0.0f), 63.0f);
            int y0 = (int)floorf(y); y0 = min(max(y0, 0), HGT - 2);
            int x0 = (int)floorf(x); x0 = min(max(x0, 0), WID - 2);
            const float wy = y - (float)y0;
            const float wx = x - (float)x0;
            const int base = (y0 << 6) + x0;
            atomicAdd(&acc[base],           (1.0f - wy) * (1.0f - wx));
            atomicAdd(&acc[base + 1],       (1.0f - wy) * wx);
            atomicAdd(&acc[base + WID],     wy * (1.0f - wx));
            atomicAdd(&acc[base + WID + 1], wy * wx);
        }
    }
    __syncthreads();   // drains vmcnt -- data has arrived during the scatter

    // ---- Phase B: drain 16 registered float4 against the LDS map ----
    float a0 = 0.0f, a1 = 0.0f, a2 = 0.0f, a3 = 0.0f;
    #pragma unroll
    for (int s = 0; s < 16; ++s) {
        const float4 av =
            *reinterpret_cast<const float4*>(acc + s * 256 + lane * 4);
        if ((s & 3) == 0) {
            a0 = fmaf(av.x, d[s].x, a0); a0 = fmaf(av.y, d[s].y, a0);
            a0 = fmaf(av.z, d[s].z, a0); a0 = fmaf(av.w, d[s].w, a0);
        } else if ((s & 3) == 1) {
            a1 = fmaf(av.x, d[s].x, a1); a1 = fmaf(av.y, d[s].y, a1);
            a1 = fmaf(av.z, d[s].z, a1); a1 = fmaf(av.w, d[s].w, a1);
        } else if ((s & 3) == 2) {
            a2 = fmaf(av.x, d[s].x, a2); a2 = fmaf(av.y, d[s].y, a2);
            a2 = fmaf(av.z, d[s].z, a2); a2 = fmaf(av.w, d[s].w, a2);
        } else {
            a3 = fmaf(av.x, d[s].x, a3); a3 = fmaf(av.y, d[s].y, a3);
            a3 = fmaf(av.z, d[s].z, a3); a3 = fmaf(av.w, d[s].w, a3);
        }
    }
    float sum = (a0 + a1) + (a2 + a3);

    // ---- wave-64 register-only shuffle reduce; no further barriers ----
    #pragma unroll
    for (int off = 32; off > 0; off >>= 1)
        sum += __shfl_down(sum, off, 64);

    if (lane == 0)
        out[(b << 8) + g * CPB + w] = sum * (1.0f / (float)HW);  // fold mean
}

extern "C" void kernel_launch(void* const* d_in, const int* in_sizes, int n_in,
                              void* d_out, int out_size, void* d_ws, size_t ws_size,
                              hipStream_t stream) {
    const float* data   = (const float*)d_in[0];  // fp32 [32,256,64,64]
    const float* offset = (const float*)d_in[1];  // fp32 [32,2,64,64]
    const float* ts     = (const float*)d_in[2];  // fp32 scalar

    float* out = (float*)d_out;                   // [32, 256] fp32
    (void)d_ws; (void)ws_size;                    // workspace intentionally unused

    fused_bilinear_pool<<<BATCH * CPB, 1024, 0, stream>>>(data, offset, ts, out);
}